// Round 1
// baseline (2139.414 us; speedup 1.0000x reference)
//
#include <hip/hip_runtime.h>
#include <hip/hip_bf16.h>
#include <stdint.h>

// Problem constants
#define Bb 16
#define Ss 2048
#define Dd 1024
#define Hh 1024
#define Rr 16
#define Mm 32768   // B*S

typedef __attribute__((ext_vector_type(4))) float f32x4;
typedef __attribute__((ext_vector_type(8))) short bf16x8;

// RNE fp32 -> bf16 bits
__device__ __forceinline__ unsigned short f2bf(float f) {
    union { float f; uint32_t u; } c; c.f = f;
    uint32_t u = c.u + 0x7fffu + ((c.u >> 16) & 1u);
    return (unsigned short)(u >> 16);
}
__device__ __forceinline__ float bfbits2f(uint32_t bits) {
    union { uint32_t u; float f; } c; c.u = bits << 16; return c.f;
}

// async global->LDS, 16B per lane. LDS dest = uniform base + lane*16.
__device__ __forceinline__ void gld16(const void* gsrc, void* ldst) {
    __builtin_amdgcn_global_load_lds(
        (const __attribute__((address_space(1))) unsigned int*)gsrc,
        (__attribute__((address_space(3))) unsigned int*)ldst, 16, 0, 0);
}

// Raw workgroup barrier WITHOUT the vmcnt(0) drain __syncthreads carries.
// lgkmcnt(0) makes LDS writes visible across waves; outstanding global
// (prefetch) loads stay in flight.
// imm 0xC07F = vmcnt(63) expcnt(7) lgkmcnt(0)  [gfx9 encoding]
__device__ __forceinline__ void softbar() {
    __asm volatile("" ::: "memory");
    __builtin_amdgcn_s_waitcnt(0xC07F);
    __builtin_amdgcn_s_barrier();
    __asm volatile("" ::: "memory");
}

// ---------------------------------------------------------------------------
// Kernel 1: convert x, Wa, Wu to bf16 (flat, 4 elems/thread)
// ---------------------------------------------------------------------------
__global__ __launch_bounds__(256) void k_convert(
    const float* __restrict__ x, const float* __restrict__ Wa,
    const float* __restrict__ Wu,
    unsigned short* __restrict__ xb, unsigned short* __restrict__ Wab,
    unsigned short* __restrict__ Wub)
{
    long e = ((long)blockIdx.x * 256 + threadIdx.x) * 4;
    const long nx = (long)Mm * Dd;        // 33,554,432
    const long nw = (long)Hh * Dd;        // 1,048,576
    const float* src; unsigned short* dst; long o;
    if (e < nx)            { src = x;  dst = xb;  o = e; }
    else if (e < nx + nw)  { src = Wa; dst = Wab; o = e - nx; }
    else                   { src = Wu; dst = Wub; o = e - nx - nw; }
    float4 f = *(const float4*)(src + o);
    ushort4 r;
    r.x = f2bf(f.x); r.y = f2bf(f.y); r.z = f2bf(f.z); r.w = f2bf(f.w);
    *(ushort4*)(dst + o) = r;
}

// ---------------------------------------------------------------------------
// Kernel 2: C[M,1024] = Xb @ W^T (+bias, optional sigmoid), bf16 MFMA.
// Outputs bf16 (halves epilogue writes AND the scan's stream reads).
// ---------------------------------------------------------------------------
__global__ __launch_bounds__(256) void k_gemm(
    const unsigned short* __restrict__ Xb,   // [M, D] bf16 bits
    const unsigned short* __restrict__ Wab,  // [H, D]
    const unsigned short* __restrict__ Wub,  // [H, D]
    const float* __restrict__ ba, const float* __restrict__ bu,
    unsigned short* __restrict__ outA, unsigned short* __restrict__ outU)
{
    __shared__ short At[128 * 32];
    __shared__ short Bt[128 * 32];

    const int tid  = threadIdx.x;
    const int lane = tid & 63;
    const int wave = tid >> 6;
    const int bm = blockIdx.x;
    const int bn = blockIdx.y;
    const int region = bn >> 3;            // 0: a, 1: u_in
    const int nbase = (bn & 7) * 128;

    const short* Ag = (const short*)Xb;
    const short* Bg = (const short*)(region ? Wub : Wab);
    const float* bias = region ? bu : ba;
    unsigned short* outp = region ? outU : outA;

    const int wm = wave & 1, wn = wave >> 1;
    const int srow = lane >> 2, sseg = lane & 3;   // staging: 4 lanes/row
    const int mrow = lane & 15, kb = lane >> 4;    // fragment lane mapping

    f32x4 acc[4][4] = {};

    for (int kt = 0; kt < 32; ++kt) {
        __syncthreads();
        const int k0 = kt * 32;
        #pragma unroll
        for (int p = 0; p < 2; ++p) {
            const int row = p * 64 + wave * 16 + srow;
            const short* ga = Ag + (long)(bm * 128 + row) * Dd + k0 + sseg * 8;
            gld16((const void*)ga, (void*)&At[p * 2048 + wave * 512]);
            const short* gb = Bg + (long)(nbase + row) * Dd + k0 + sseg * 8;
            gld16((const void*)gb, (void*)&Bt[p * 2048 + wave * 512]);
        }
        __syncthreads();

        bf16x8 af[4], bq[4];
        #pragma unroll
        for (int i = 0; i < 4; ++i) {
            af[i] = *(const bf16x8*)&At[(wm * 64 + i * 16 + mrow) * 32 + kb * 8];
            bq[i] = *(const bf16x8*)&Bt[(wn * 64 + i * 16 + mrow) * 32 + kb * 8];
        }
        #pragma unroll
        for (int i = 0; i < 4; ++i)
            #pragma unroll
            for (int j = 0; j < 4; ++j)
                acc[i][j] = __builtin_amdgcn_mfma_f32_16x16x32_bf16(
                    af[i], bq[j], acc[i][j], 0, 0, 0);
    }

    // Epilogue: C/D layout col=lane&15, row=(lane>>4)*4+reg (m89-verified)
    const int col = lane & 15, rq = lane >> 4;
    #pragma unroll
    for (int j = 0; j < 4; ++j) {
        const int n = nbase + wn * 64 + j * 16 + col;
        const float bv = bias[n];
        #pragma unroll
        for (int i = 0; i < 4; ++i) {
            const int mb = bm * 128 + wm * 64 + i * 16 + rq * 4;
            #pragma unroll
            for (int r = 0; r < 4; ++r) {
                float vv = acc[i][j][r] + bv;
                if (region == 0) vv = 1.0f / (1.0f + __expf(-vv));
                outp[(long)(mb + r) * Hh + n] = f2bf(vv);
            }
        }
    }
}

// ---------------------------------------------------------------------------
// Kernel 3: g[M,16] = x @ Wg^T + bg (fp32, tiny N)
// ---------------------------------------------------------------------------
__global__ __launch_bounds__(256) void k_g(
    const float* __restrict__ x, const float* __restrict__ Wg,
    const float* __restrict__ bg, float* __restrict__ g)
{
    const int tid = threadIdx.x;
    const int r = tid & 15, ml = tid >> 4;
    const long m = (long)blockIdx.x * 16 + ml;
    const float4* xr = (const float4*)(x + m * Dd);
    const float4* wr = (const float4*)(Wg + (long)r * Dd);
    float acc = 0.0f;
    #pragma unroll 4
    for (int k = 0; k < Dd / 4; ++k) {
        float4 a = xr[k], b = wr[k];
        acc = fmaf(a.x, b.x, acc); acc = fmaf(a.y, b.y, acc);
        acc = fmaf(a.z, b.z, acc); acc = fmaf(a.w, b.w, acc);
    }
    g[m * Rr + r] = acc + bg[r];
}

// ---------------------------------------------------------------------------
// Kernel 4: sequential scan. One block per b (16 blocks x 1024 threads).
// NEW 2-phase structure (was 3-phase):
//  A: wave w covers h in [64w,64w+64); lane: 4x f32x4 pk-FMAs for r=lane&15
//     over its 16-h sub-block (sub=lane>>4), hsum, 2 shuffle hops (xor16,32);
//     lanes<16 write raw wave-partial -> cacc[r][w] (w-contiguous, stride 20).
//  C: each lane reads ONE f32x4 quad of cacc (its r row, 4 w's), hsums,
//     2 shuffle hops -> full sum over 16 waves; scale by per-lane prefetched
//     g_t[lane&15] -> q complete in every lane. 16x v_readlane -> SGPRs,
//     lr = tree FMA with SGPR sources; s = a*s + u + lr; write state.
// This kills the old phase B (wave-0 serial section), the qbuf broadcast
// reads (16 waves x 4 ds_read_b128 of the SAME 64B), and one of the three
// barriers per step. fp32 state in LDS; a/u streams bf16; softbar keeps the
// depth-4 global prefetch ring in flight across all barriers.
// ---------------------------------------------------------------------------
__global__ __launch_bounds__(1024) void k_scan(
    const unsigned short* __restrict__ a,    // [B,S,H] bf16
    const unsigned short* __restrict__ uin,  // [B,S,H] bf16
    const float* __restrict__ g,    // [B,S,R]
    const float* __restrict__ u,    // [H,R]
    const float* __restrict__ v,    // [H,R]
    float* __restrict__ out)        // [B,H]
{
    __shared__ __align__(16) float sbf[Hh];        // fp32 state, 4 KB
    __shared__ __align__(16) float cacc[16 * 20];  // [r][w], stride 20

    const int tid  = threadIdx.x;
    const int lane = tid & 63;
    const int wave = tid >> 6;
    const int sub  = lane >> 4;      // h sub-block within wave / quad in C
    const int ra   = lane & 15;      // r owned in phase A and C
    const int b = blockIdx.x;

    // phase-A consts: v[64w + 16*sub + 4c + k][ra], packed f32x4 per chunk
    const int hA = wave * 64 + sub * 16;
    f32x4 vr4[4];
    #pragma unroll
    for (int c = 0; c < 4; ++c) {
        f32x4 t;
        t.x = v[(hA + 4 * c + 0) * Rr + ra];
        t.y = v[(hA + 4 * c + 1) * Rr + ra];
        t.z = v[(hA + 4 * c + 2) * Rr + ra];
        t.w = v[(hA + 4 * c + 3) * Rr + ra];
        vr4[c] = t;
    }
    // phase-C consts: U row for h = tid
    float ur[16];
    #pragma unroll
    for (int j = 0; j < 4; ++j) {
        float4 t4 = *(const float4*)&u[tid * Rr + j * 4];
        ur[j*4+0] = t4.x; ur[j*4+1] = t4.y; ur[j*4+2] = t4.z; ur[j*4+3] = t4.w;
    }

    const unsigned short* ap = a   + (long)b * Ss * Hh + tid;
    const unsigned short* up = uin + (long)b * Ss * Hh + tid;
    const float*          gp = g   + (long)b * Ss * Rr + ra;   // all lanes

    float s = 0.0f;
    uint32_t pa[4], pu[4]; float pg[4];
    #pragma unroll
    for (int t = 0; t < 4; ++t) {
        pa[t] = ap[t * Hh]; pu[t] = up[t * Hh]; pg[t] = gp[t * Rr];
    }
    ap += 4 * Hh; up += 4 * Hh; gp += 4 * Rr;

    sbf[tid] = 0.0f;
    __syncthreads();

    const float* spA = &sbf[hA];

#define STEP(R, PF) do {                                                    \
    /* A: partial_{r=ra} over 16 h's (pk vector FMAs + tree hsum) */        \
    f32x4 s0 = *(const f32x4*)(spA);                                        \
    f32x4 s1 = *((const f32x4*)(spA) + 1);                                  \
    f32x4 s2 = *((const f32x4*)(spA) + 2);                                  \
    f32x4 s3 = *((const f32x4*)(spA) + 3);                                  \
    f32x4 acc = s0 * vr4[0];                                                \
    acc = s1 * vr4[1] + acc;                                                \
    acc = s2 * vr4[2] + acc;                                                \
    acc = s3 * vr4[3] + acc;                                                \
    float part = (acc.x + acc.y) + (acc.z + acc.w);                         \
    part += __shfl_xor(part, 16);                                           \
    part += __shfl_xor(part, 32);                                           \
    if (lane < 16) cacc[20 * ra + wave] = part;                             \
    /* capture this step's stream values, then issue prefetch early so   */ \
    /* the global loads fly during the barrier wait                      */ \
    float av = bfbits2f(pa[R]);                                             \
    float uv = bfbits2f(pu[R]);                                             \
    float gv = pg[R];                                                       \
    if (PF) {                                                               \
        pa[R] = *ap; ap += Hh;                                              \
        pu[R] = *up; up += Hh;                                              \
        pg[R] = *gp; gp += Rr;                                              \
    }                                                                       \
    softbar(); /* bar1: cacc visible */                                     \
    /* C: quad-read cross-wave partials, butterfly -> full q per lane */    \
    f32x4 c4 = *(const f32x4*)&cacc[20 * ra + 4 * sub];                     \
    float qv = (c4.x + c4.y) + (c4.z + c4.w);                               \
    qv += __shfl_xor(qv, 16);                                               \
    qv += __shfl_xor(qv, 32);                                               \
    qv *= gv;                                                               \
    float qs[16];                                                           \
    _Pragma("unroll")                                                       \
    for (int r_ = 0; r_ < 16; ++r_)                                         \
        qs[r_] = __int_as_float(                                            \
            __builtin_amdgcn_readlane(__float_as_int(qv), r_));             \
    float l0 = qs[0] * ur[0];                                               \
    l0 = fmaf(qs[1], ur[1], l0);  l0 = fmaf(qs[2], ur[2], l0);              \
    l0 = fmaf(qs[3], ur[3], l0);                                            \
    float l1 = qs[4] * ur[4];                                               \
    l1 = fmaf(qs[5], ur[5], l1);  l1 = fmaf(qs[6], ur[6], l1);              \
    l1 = fmaf(qs[7], ur[7], l1);                                            \
    float l2 = qs[8] * ur[8];                                               \
    l2 = fmaf(qs[9], ur[9], l2);  l2 = fmaf(qs[10], ur[10], l2);            \
    l2 = fmaf(qs[11], ur[11], l2);                                          \
    float l3 = qs[12] * ur[12];                                             \
    l3 = fmaf(qs[13], ur[13], l3); l3 = fmaf(qs[14], ur[14], l3);           \
    l3 = fmaf(qs[15], ur[15], l3);                                          \
    float lr = (l0 + l1) + (l2 + l3);                                       \
    s = fmaf(av, s, uv + lr);                                               \
    sbf[tid] = s;                                                           \
    softbar(); /* bar2: state visible */                                    \
} while (0)

    for (int t4 = 0; t4 < Ss / 4 - 1; ++t4) {
        STEP(0, 1); STEP(1, 1); STEP(2, 1); STEP(3, 1);
    }
    STEP(0, 0); STEP(1, 0); STEP(2, 0); STEP(3, 0);
#undef STEP

    out[(long)b * Hh + tid] = s;
}

// ---------------------------------------------------------------------------
extern "C" void kernel_launch(void* const* d_in, const int* in_sizes, int n_in,
                              void* d_out, int out_size, void* d_ws, size_t ws_size,
                              hipStream_t stream)
{
    const float* x  = (const float*)d_in[0];
    const float* Wa = (const float*)d_in[1];
    const float* ba = (const float*)d_in[2];
    const float* Wg = (const float*)d_in[3];
    const float* bg = (const float*)d_in[4];
    const float* Wu = (const float*)d_in[5];
    const float* bu = (const float*)d_in[6];
    const float* u  = (const float*)d_in[7];
    const float* v  = (const float*)d_in[8];
    float* out = (float*)d_out;

    char* ws = (char*)d_ws;
    unsigned short* xb   = (unsigned short*)(ws);                // 67,108,864 B
    unsigned short* Wab  = (unsigned short*)(ws + 67108864);     //  2,097,152 B
    unsigned short* Wub  = (unsigned short*)(ws + 69206016);     //  2,097,152 B
    unsigned short* abuf = (unsigned short*)(ws + 71303168);     // 67,108,864 B (bf16)
    unsigned short* ubuf = (unsigned short*)(ws + 138412032);    // 67,108,864 B (bf16)
    float*          gbuf = (float*)(ws + 205520896);             //  2,097,152 B

    hipLaunchKernelGGL(k_convert, dim3(34816), dim3(256), 0, stream,
                       x, Wa, Wu, xb, Wab, Wub);
    hipLaunchKernelGGL(k_gemm, dim3(256, 16), dim3(256), 0, stream,
                       xb, Wab, Wub, ba, bu, abuf, ubuf);
    hipLaunchKernelGGL(k_g, dim3(2048), dim3(256), 0, stream,
                       x, Wg, bg, gbuf);
    hipLaunchKernelGGL(k_scan, dim3(Bb), dim3(1024), 0, stream,
                       abuf, ubuf, gbuf, u, v, out);
}

// Round 2
// 1825.890 us; speedup vs baseline: 1.1717x; 1.1717x over previous
//
#include <hip/hip_runtime.h>
#include <hip/hip_bf16.h>
#include <stdint.h>

// Problem constants
#define Bb 16
#define Ss 2048
#define Dd 1024
#define Hh 1024
#define Rr 16
#define Mm 32768   // B*S

typedef __attribute__((ext_vector_type(4))) float f32x4;
typedef __attribute__((ext_vector_type(8))) short bf16x8;
typedef __attribute__((ext_vector_type(2))) _Float16 h2;

// RNE fp32 -> bf16 bits
__device__ __forceinline__ unsigned short f2bf(float f) {
    union { float f; uint32_t u; } c; c.f = f;
    uint32_t u = c.u + 0x7fffu + ((c.u >> 16) & 1u);
    return (unsigned short)(u >> 16);
}
__device__ __forceinline__ float bfbits2f(uint32_t bits) {
    union { uint32_t u; float f; } c; c.u = bits << 16; return c.f;
}
__device__ __forceinline__ h2 u2h(unsigned int x) {
    union { unsigned int u; h2 h; } c; c.u = x; return c.h;
}
__device__ __forceinline__ h2 mkh2(float a, float b) {
    h2 r; r.x = (_Float16)a; r.y = (_Float16)b; return r;
}

// v_dot2_f32_f16: c + a.x*b.x + a.y*b.y (f32 accumulate)
__device__ __forceinline__ float DOT2(h2 a, h2 b, float c) {
#if __has_builtin(__builtin_amdgcn_fdot2)
    return __builtin_amdgcn_fdot2(a, b, c, false);
#else
    return fmaf((float)a.x, (float)b.x, fmaf((float)a.y, (float)b.y, c));
#endif
}

// async global->LDS, 16B per lane. LDS dest = uniform base + lane*16.
__device__ __forceinline__ void gld16(const void* gsrc, void* ldst) {
    __builtin_amdgcn_global_load_lds(
        (const __attribute__((address_space(1))) unsigned int*)gsrc,
        (__attribute__((address_space(3))) unsigned int*)ldst, 16, 0, 0);
}

// Raw workgroup barrier WITHOUT the vmcnt(0) drain __syncthreads carries.
// lgkmcnt(0) makes LDS writes visible across waves; outstanding global
// (prefetch) loads stay in flight.
// imm 0xC07F = vmcnt(63) expcnt(7) lgkmcnt(0)  [gfx9 encoding]
__device__ __forceinline__ void softbar() {
    __asm volatile("" ::: "memory");
    __builtin_amdgcn_s_waitcnt(0xC07F);
    __builtin_amdgcn_s_barrier();
    __asm volatile("" ::: "memory");
}

// ---------------------------------------------------------------------------
// Kernel 1: convert x, Wa, Wu to bf16 (flat, 4 elems/thread)
// ---------------------------------------------------------------------------
__global__ __launch_bounds__(256) void k_convert(
    const float* __restrict__ x, const float* __restrict__ Wa,
    const float* __restrict__ Wu,
    unsigned short* __restrict__ xb, unsigned short* __restrict__ Wab,
    unsigned short* __restrict__ Wub)
{
    long e = ((long)blockIdx.x * 256 + threadIdx.x) * 4;
    const long nx = (long)Mm * Dd;        // 33,554,432
    const long nw = (long)Hh * Dd;        // 1,048,576
    const float* src; unsigned short* dst; long o;
    if (e < nx)            { src = x;  dst = xb;  o = e; }
    else if (e < nx + nw)  { src = Wa; dst = Wab; o = e - nx; }
    else                   { src = Wu; dst = Wub; o = e - nx - nw; }
    float4 f = *(const float4*)(src + o);
    ushort4 r;
    r.x = f2bf(f.x); r.y = f2bf(f.y); r.z = f2bf(f.z); r.w = f2bf(f.w);
    *(ushort4*)(dst + o) = r;
}

// ---------------------------------------------------------------------------
// Kernel 2: C[M,1024] = Xb @ W^T (+bias, optional sigmoid), bf16 MFMA.
// ---------------------------------------------------------------------------
__global__ __launch_bounds__(256) void k_gemm(
    const unsigned short* __restrict__ Xb,   // [M, D] bf16 bits
    const unsigned short* __restrict__ Wab,  // [H, D]
    const unsigned short* __restrict__ Wub,  // [H, D]
    const float* __restrict__ ba, const float* __restrict__ bu,
    unsigned short* __restrict__ outA, unsigned short* __restrict__ outU)
{
    __shared__ short At[128 * 32];
    __shared__ short Bt[128 * 32];

    const int tid  = threadIdx.x;
    const int lane = tid & 63;
    const int wave = tid >> 6;
    const int bm = blockIdx.x;
    const int bn = blockIdx.y;
    const int region = bn >> 3;            // 0: a, 1: u_in
    const int nbase = (bn & 7) * 128;

    const short* Ag = (const short*)Xb;
    const short* Bg = (const short*)(region ? Wub : Wab);
    const float* bias = region ? bu : ba;
    unsigned short* outp = region ? outU : outA;

    const int wm = wave & 1, wn = wave >> 1;
    const int srow = lane >> 2, sseg = lane & 3;   // staging: 4 lanes/row
    const int mrow = lane & 15, kb = lane >> 4;    // fragment lane mapping

    f32x4 acc[4][4] = {};

    for (int kt = 0; kt < 32; ++kt) {
        __syncthreads();
        const int k0 = kt * 32;
        #pragma unroll
        for (int p = 0; p < 2; ++p) {
            const int row = p * 64 + wave * 16 + srow;
            const short* ga = Ag + (long)(bm * 128 + row) * Dd + k0 + sseg * 8;
            gld16((const void*)ga, (void*)&At[p * 2048 + wave * 512]);
            const short* gb = Bg + (long)(nbase + row) * Dd + k0 + sseg * 8;
            gld16((const void*)gb, (void*)&Bt[p * 2048 + wave * 512]);
        }
        __syncthreads();

        bf16x8 af[4], bq[4];
        #pragma unroll
        for (int i = 0; i < 4; ++i) {
            af[i] = *(const bf16x8*)&At[(wm * 64 + i * 16 + mrow) * 32 + kb * 8];
            bq[i] = *(const bf16x8*)&Bt[(wn * 64 + i * 16 + mrow) * 32 + kb * 8];
        }
        #pragma unroll
        for (int i = 0; i < 4; ++i)
            #pragma unroll
            for (int j = 0; j < 4; ++j)
                acc[i][j] = __builtin_amdgcn_mfma_f32_16x16x32_bf16(
                    af[i], bq[j], acc[i][j], 0, 0, 0);
    }

    // Epilogue: C/D layout col=lane&15, row=(lane>>4)*4+reg (m89-verified)
    const int col = lane & 15, rq = lane >> 4;
    #pragma unroll
    for (int j = 0; j < 4; ++j) {
        const int n = nbase + wn * 64 + j * 16 + col;
        const float bv = bias[n];
        #pragma unroll
        for (int i = 0; i < 4; ++i) {
            const int mb = bm * 128 + wm * 64 + i * 16 + rq * 4;
            #pragma unroll
            for (int r = 0; r < 4; ++r) {
                float vv = acc[i][j][r] + bv;
                if (region == 0) vv = 1.0f / (1.0f + __expf(-vv));
                outp[(long)(mb + r) * Hh + n] = f2bf(vv);
            }
        }
    }
}

// ---------------------------------------------------------------------------
// Kernel 3: g[M,16] = x @ Wg^T + bg (fp32, tiny N)
// ---------------------------------------------------------------------------
__global__ __launch_bounds__(256) void k_g(
    const float* __restrict__ x, const float* __restrict__ Wg,
    const float* __restrict__ bg, float* __restrict__ g)
{
    const int tid = threadIdx.x;
    const int r = tid & 15, ml = tid >> 4;
    const long m = (long)blockIdx.x * 16 + ml;
    const float4* xr = (const float4*)(x + m * Dd);
    const float4* wr = (const float4*)(Wg + (long)r * Dd);
    float acc = 0.0f;
    #pragma unroll 4
    for (int k = 0; k < Dd / 4; ++k) {
        float4 a = xr[k], b = wr[k];
        acc = fmaf(a.x, b.x, acc); acc = fmaf(a.y, b.y, acc);
        acc = fmaf(a.z, b.z, acc); acc = fmaf(a.w, b.w, acc);
    }
    g[m * Rr + r] = acc + bg[r];
}

// ---------------------------------------------------------------------------
// Kernel 4: sequential scan. One block per b (16 blocks x 1024 threads).
// Round-0 3-phase structure (1247 us measured), with the LDS-return-bus
// traffic HALVED via fp16 communication copies:
//  - s (recurrence state) stays fp32 in the owning thread's register.
//  - sh[1024] is an fp16 SHADOW of the state, written by each thread in
//    phase C, read by phase A as 2x ds_read_b128 (32 B/lane, was 64 B).
//    Bank check: windows at dwords {0,8,16,24} / {4,12,20,28} per wave,
//    16-lane broadcast each -> conflict-free.
//  - qh[16] is fp16 q, phase-C broadcast read is 2x b128 of IDENTICAL
//    address across all lanes (was 4x b128) -> free broadcast.
//  - products via v_dot2_f32_f16 (f32 accumulate): 8 dot2 replace 16 FMAs
//    in BOTH phase A and phase C -> per-lane VALU down ~30%.
// Precision: only y = V^T s and lr = U q see fp16 rounding (low-rank
// correction path, |lr| ~ 0.03); a/u streams already bf16. State update
// itself stays fp32.
// ---------------------------------------------------------------------------
__global__ __launch_bounds__(1024) void k_scan(
    const unsigned short* __restrict__ a,    // [B,S,H] bf16
    const unsigned short* __restrict__ uin,  // [B,S,H] bf16
    const float* __restrict__ g,    // [B,S,R]
    const float* __restrict__ u,    // [H,R]
    const float* __restrict__ v,    // [H,R]
    float* __restrict__ out)        // [B,H]
{
    __shared__ __align__(16) _Float16 sh[Hh];      // fp16 state shadow, 2 KB
    __shared__ __align__(16) float cacc[16 * 20];  // [r][w], stride 20
    __shared__ __align__(16) _Float16 qh[16];      // fp16 q, 32 B

    const int tid  = threadIdx.x;
    const int lane = tid & 63;
    const int wave = tid >> 6;
    const int sub  = lane >> 4;      // h sub-block within wave
    const int ra   = lane & 15;      // r owned in phase A
    const int b = blockIdx.x;

    // phase-A consts: fp16 pairs (v[hA+2j][ra], v[hA+2j+1][ra])
    const int hA = wave * 64 + sub * 16;
    h2 vr2[8];
    #pragma unroll
    for (int j = 0; j < 8; ++j)
        vr2[j] = mkh2(v[(hA + 2 * j) * Rr + ra], v[(hA + 2 * j + 1) * Rr + ra]);
    // phase-C consts: fp16 pairs of U row for h = tid
    h2 ur2[8];
    #pragma unroll
    for (int j = 0; j < 4; ++j) {
        float4 t4 = *(const float4*)&u[tid * Rr + j * 4];
        ur2[2 * j]     = mkh2(t4.x, t4.y);
        ur2[2 * j + 1] = mkh2(t4.z, t4.w);
    }

    const unsigned short* ap = a   + (long)b * Ss * Hh + tid;
    const unsigned short* up = uin + (long)b * Ss * Hh + tid;
    const float*          gp = g   + (long)b * Ss * Rr + tid;  // tid<16 only

    float s = 0.0f;
    uint32_t pa[4], pu[4]; float pg[4];
    #pragma unroll
    for (int t = 0; t < 4; ++t) { pa[t] = ap[t * Hh]; pu[t] = up[t * Hh]; }
    ap += 4 * Hh; up += 4 * Hh;
    if (tid < 16) {
        #pragma unroll
        for (int t = 0; t < 4; ++t) pg[t] = gp[t * Rr];
        gp += 4 * Rr;
    }

    sh[tid] = (_Float16)0.0f;
    __syncthreads();

    const _Float16* spA16 = &sh[hA];

#define STEP(R, PF) do {                                                    \
    /* A: partial_{r=ra} over 16 h's via 8x v_dot2_f32_f16 */               \
    uint4 sA = *(const uint4*)(spA16);                                      \
    uint4 sB = *(const uint4*)(spA16 + 8);                                  \
    float part;                                                             \
    part = DOT2(u2h(sA.x), vr2[0], 0.0f);                                   \
    part = DOT2(u2h(sA.y), vr2[1], part);                                   \
    part = DOT2(u2h(sA.z), vr2[2], part);                                   \
    part = DOT2(u2h(sA.w), vr2[3], part);                                   \
    part = DOT2(u2h(sB.x), vr2[4], part);                                   \
    part = DOT2(u2h(sB.y), vr2[5], part);                                   \
    part = DOT2(u2h(sB.z), vr2[6], part);                                   \
    part = DOT2(u2h(sB.w), vr2[7], part);                                   \
    part += __shfl_xor(part, 16);                                           \
    part += __shfl_xor(part, 32);                                           \
    if (lane < 16) cacc[20 * ra + wave] = part;                             \
    softbar(); /* bar1 */                                                   \
    /* B: q[r] = g_t[r] * sum_w cacc[r][w]  (wave 0, lanes<16) */           \
    if (tid < 16) {                                                         \
        const float* cr = &cacc[20 * tid];                                  \
        f32x4 c0 = *(const f32x4*)(cr);                                     \
        f32x4 c1 = *((const f32x4*)(cr) + 1);                               \
        f32x4 c2 = *((const f32x4*)(cr) + 2);                               \
        f32x4 c3 = *((const f32x4*)(cr) + 3);                               \
        f32x4 cs = (c0 + c1) + (c2 + c3);                                   \
        qh[tid] = (_Float16)(pg[R] * ((cs.x + cs.y) + (cs.z + cs.w)));      \
        if (PF) { pg[R] = *gp; gp += Rr; }                                  \
    }                                                                       \
    softbar(); /* bar2 */                                                   \
    /* C: s = a*s + u + sum_r q[r]*U[h][r]  (8x dot2, broadcast read) */    \
    uint4 qA = *(const uint4*)(qh);                                         \
    uint4 qB = *(const uint4*)(qh + 8);                                     \
    float lr;                                                               \
    lr = DOT2(u2h(qA.x), ur2[0], 0.0f);                                     \
    lr = DOT2(u2h(qA.y), ur2[1], lr);                                       \
    lr = DOT2(u2h(qA.z), ur2[2], lr);                                       \
    lr = DOT2(u2h(qA.w), ur2[3], lr);                                       \
    lr = DOT2(u2h(qB.x), ur2[4], lr);                                       \
    lr = DOT2(u2h(qB.y), ur2[5], lr);                                       \
    lr = DOT2(u2h(qB.z), ur2[6], lr);                                       \
    lr = DOT2(u2h(qB.w), ur2[7], lr);                                       \
    s = fmaf(bfbits2f(pa[R]), s, bfbits2f(pu[R]) + lr);                     \
    sh[tid] = (_Float16)s;                                                  \
    if (PF) {                                                               \
        pa[R] = *ap; ap += Hh;                                              \
        pu[R] = *up; up += Hh;                                              \
    }                                                                       \
    softbar(); /* bar3 */                                                   \
} while (0)

    for (int t4 = 0; t4 < Ss / 4 - 1; ++t4) {
        STEP(0, 1); STEP(1, 1); STEP(2, 1); STEP(3, 1);
    }
    STEP(0, 0); STEP(1, 0); STEP(2, 0); STEP(3, 0);
#undef STEP

    out[(long)b * Hh + tid] = s;
}

// ---------------------------------------------------------------------------
extern "C" void kernel_launch(void* const* d_in, const int* in_sizes, int n_in,
                              void* d_out, int out_size, void* d_ws, size_t ws_size,
                              hipStream_t stream)
{
    const float* x  = (const float*)d_in[0];
    const float* Wa = (const float*)d_in[1];
    const float* ba = (const float*)d_in[2];
    const float* Wg = (const float*)d_in[3];
    const float* bg = (const float*)d_in[4];
    const float* Wu = (const float*)d_in[5];
    const float* bu = (const float*)d_in[6];
    const float* u  = (const float*)d_in[7];
    const float* v  = (const float*)d_in[8];
    float* out = (float*)d_out;

    char* ws = (char*)d_ws;
    unsigned short* xb   = (unsigned short*)(ws);                // 67,108,864 B
    unsigned short* Wab  = (unsigned short*)(ws + 67108864);     //  2,097,152 B
    unsigned short* Wub  = (unsigned short*)(ws + 69206016);     //  2,097,152 B
    unsigned short* abuf = (unsigned short*)(ws + 71303168);     // 67,108,864 B (bf16)
    unsigned short* ubuf = (unsigned short*)(ws + 138412032);    // 67,108,864 B (bf16)
    float*          gbuf = (float*)(ws + 205520896);             //  2,097,152 B

    hipLaunchKernelGGL(k_convert, dim3(34816), dim3(256), 0, stream,
                       x, Wa, Wu, xb, Wab, Wub);
    hipLaunchKernelGGL(k_gemm, dim3(256, 16), dim3(256), 0, stream,
                       xb, Wab, Wub, ba, bu, abuf, ubuf);
    hipLaunchKernelGGL(k_g, dim3(2048), dim3(256), 0, stream,
                       x, Wg, bg, gbuf);
    hipLaunchKernelGGL(k_scan, dim3(Bb), dim3(1024), 0, stream,
                       abuf, ubuf, gbuf, u, v, out);
}